// Round 3
// baseline (2891.397 us; speedup 1.0000x reference)
//
#include <hip/hip_runtime.h>

#define NE 50000
#define NN 10000
#define KH 96
#define KE 128          // padded K: 96 + bias row (=1*b2) + zeros
#define WN 6928
#define IN_SZ 156
#define EPW 32          // edges per workgroup in tp_kernel
#define NT  433         // WN/16 column tiles

typedef __attribute__((ext_vector_type(8))) short short8;
typedef __attribute__((ext_vector_type(4))) float float4v;

__device__ __forceinline__ unsigned short f2bf(float x) {
  unsigned u = __float_as_uint(x);
  unsigned r = (u + 0x7FFFu + ((u >> 16) & 1u)) >> 16;   // RNE
  return (unsigned short)r;
}
__device__ __forceinline__ float b2f(unsigned short u) {
  return __uint_as_float(((unsigned)u) << 16);
}

// ---------------- Kernel 1: h_ext = [relu(edge_attr @ W1 + b1) | 1 | 0...] in bf16 ----------------
__global__ __launch_bounds__(256) void mlp1_kernel(
    const float* __restrict__ edge_attr, const float* __restrict__ W1,
    const float* __restrict__ b1, unsigned short* __restrict__ h_ext)
{
  __shared__ float ea[8][KH];
  __shared__ float w1s[KH][KH];
  const int tid = threadIdx.x;
  const int e0 = blockIdx.x * 8;

  for (int idx = tid; idx < KH * KH; idx += 256) w1s[idx / KH][idx % KH] = W1[idx];
  for (int idx = tid; idx < 8 * KH; idx += 256) {
    int e = idx / KH, k = idx % KH;
    ea[e][k] = edge_attr[(size_t)(e0 + e) * KH + k];
  }
  __syncthreads();

  const int e = tid >> 5;
  const int lane32 = tid & 31;
  const int j0 = lane32 * 3;
  float a0 = b1[j0], a1 = b1[j0 + 1], a2 = b1[j0 + 2];
  #pragma unroll 8
  for (int k = 0; k < KH; ++k) {
    float v = ea[e][k];
    a0 = fmaf(v, w1s[k][j0], a0);
    a1 = fmaf(v, w1s[k][j0 + 1], a1);
    a2 = fmaf(v, w1s[k][j0 + 2], a2);
  }
  size_t base = (size_t)(e0 + e) * KE;
  h_ext[base + j0]     = f2bf(fmaxf(a0, 0.f));
  h_ext[base + j0 + 1] = f2bf(fmaxf(a1, 0.f));
  h_ext[base + j0 + 2] = f2bf(fmaxf(a2, 0.f));
  h_ext[base + 96 + lane32] = (lane32 == 0) ? (unsigned short)0x3F80 : (unsigned short)0;
}

// ---------------- Kernel P: W2T_ext[n][k] = bf16(W2[k][n]); k=96 -> b2[n]; 97..127 -> 0 ----------------
__global__ __launch_bounds__(256) void w2t_kernel(
    const float* __restrict__ W2, const float* __restrict__ b2,
    unsigned short* __restrict__ W2T)
{
  int idx = blockIdx.x * 256 + threadIdx.x;
  if (idx >= WN * 16) return;
  int n = idx % WN, ch = idx / WN, k0 = ch * 8;
  unsigned short o[8];
  #pragma unroll
  for (int j = 0; j < 8; ++j) {
    int k = k0 + j;
    float v = (k < KH) ? W2[(size_t)k * WN + n] : (k == KH ? b2[n] : 0.f);
    o[j] = f2bf(v);
  }
  uint4 pk;
  pk.x = o[0] | ((unsigned)o[1] << 16);
  pk.y = o[2] | ((unsigned)o[3] << 16);
  pk.z = o[4] | ((unsigned)o[5] << 16);
  pk.w = o[6] | ((unsigned)o[7] << 16);
  *(uint4*)(W2T + (size_t)n * KE + k0) = pk;
}

// ---------------- Kernel 2: MFMA w-GEMM fused with tensor product + scatter ----------------
// 512 threads = 8 waves = 4 tile-phases x 2 edge-halves. 2 wg/CU (63KB LDS) -> 16 waves/CU.
__global__ __launch_bounds__(512, 4) void tp_kernel(
    const unsigned short* __restrict__ h_ext, const float* __restrict__ node_attr,
    const int* __restrict__ edge_index, const float* __restrict__ edge_sh,
    const unsigned short* __restrict__ W2T,
    float* __restrict__ acc, int* __restrict__ icnt)
{
  __shared__ float sInl[EPW][165];                 // union: inl[e][.] then out-accumulator[e][.]
  __shared__ float sF0[2][58][EPW];                // scalar feats [fam][i][e]  (0:0e, 1:0o)
  __shared__ unsigned short sF1[2][3][68][34];     // vector feats bf16 [fam][comp][i][e]
  __shared__ float sShs[EPW][4];
  __shared__ int sSrc[EPW], sDst[EPW];

  const int tid = threadIdx.x;
  const int e0 = blockIdx.x * EPW;

  if (tid < EPW) {
    int ok = (e0 + tid) < NE;
    int s = ok ? edge_index[e0 + tid] : 0;
    int d = ok ? edge_index[NE + e0 + tid] : 0;
    sSrc[tid] = s; sDst[tid] = d;
    if (ok) atomicAdd(&icnt[s], 1);               // native int atomic
  }
  if (tid >= 128 && tid < 128 + EPW * 4) {
    int t2 = tid - 128;
    int e = t2 >> 2, c = t2 & 3;
    sShs[e][c] = ((e0 + e) < NE) ? edge_sh[(size_t)(e0 + e) * 4 + c] : 0.f;
  }
  __syncthreads();

  for (int idx = tid; idx < EPW * IN_SZ; idx += 512) {
    int e = idx / IN_SZ, f = idx - e * IN_SZ;
    sInl[e][f] = node_attr[(size_t)sDst[e] * IN_SZ + f];
  }
  __syncthreads();

  { // ---- feature construction: 16 workers per edge ----
    const int e = tid >> 4, j = tid & 15;
    const float sh0 = sShs[e][0], sx = sShs[e][1], sy = sShs[e][2], sz = sShs[e][3];
    const float i3 = 0.57735026918962576f, i2 = 0.70710678118654752f;
    for (int i = j; i < 48; i += 16) {
      float v0 = sInl[e][i], w0 = sInl[e][108 + i];
      sF0[0][i][e] = v0 * sh0;
      sF0[1][10 + i][e] = w0 * sh0;
      sF1[0][0][i][e] = f2bf(v0 * sx); sF1[0][1][i][e] = f2bf(v0 * sy); sF1[0][2][i][e] = f2bf(v0 * sz);
      sF1[1][0][20 + i][e] = f2bf(w0 * sx); sF1[1][1][20 + i][e] = f2bf(w0 * sy); sF1[1][2][20 + i][e] = f2bf(w0 * sz);
    }
    if (j < 10) {
      const int v = j;
      float ax = sInl[e][48 + 3 * v], ay = sInl[e][48 + 3 * v + 1], az = sInl[e][48 + 3 * v + 2];
      float bx = sInl[e][78 + 3 * v], by = sInl[e][78 + 3 * v + 1], bz = sInl[e][78 + 3 * v + 2];
      sF0[0][48 + v][e] = (ax * sx + ay * sy + az * sz) * i3;
      sF0[1][v][e]      = (bx * sx + by * sy + bz * sz) * i3;
      sF1[0][0][48 + v][e] = f2bf(ax * sh0); sF1[0][1][48 + v][e] = f2bf(ay * sh0); sF1[0][2][48 + v][e] = f2bf(az * sh0);
      sF1[0][0][58 + v][e] = f2bf((by * sz - bz * sy) * i2);
      sF1[0][1][58 + v][e] = f2bf((bz * sx - bx * sz) * i2);
      sF1[0][2][58 + v][e] = f2bf((bx * sy - by * sx) * i2);
      sF1[1][0][v][e] = f2bf((ay * sz - az * sy) * i2);
      sF1[1][1][v][e] = f2bf((az * sx - ax * sz) * i2);
      sF1[1][2][v][e] = f2bf((ax * sy - ay * sx) * i2);
      sF1[1][0][10 + v][e] = f2bf(bx * sh0); sF1[1][1][10 + v][e] = f2bf(by * sh0); sF1[1][2][10 + v][e] = f2bf(bz * sh0);
    }
  }
  __syncthreads();

  for (int idx = tid; idx < EPW * IN_SZ; idx += 512) {  // zero accumulator (kills inl)
    int e = idx / IN_SZ, f = idx - e * IN_SZ;
    sInl[e][f] = 0.f;
  }
  __syncthreads();

  // ---- main loop ----
  const int wv = tid >> 6;            // 0..7
  const int m  = wv & 1;              // edge half (16 edges)
  const int tphase = wv >> 1;         // 0..3
  const int l = tid & 15, q = (tid >> 4) & 3;

  short8 Af[4];
  {
    size_t erow = (size_t)(e0 + m * 16 + l) * KE;   // h_ext padded to 50016 rows
    #pragma unroll
    for (int s = 0; s < 4; ++s)
      Af[s] = *(const short8*)(h_ext + erow + s * 32 + q * 8);
  }
  short8 Bf[4];
  {
    size_t brow = (size_t)(tphase * 16 + l) * KE;
    #pragma unroll
    for (int s = 0; s < 4; ++s) Bf[s] = *(const short8*)(W2T + brow + s * 32 + q * 8);
  }

  for (int t = tphase; t < NT; t += 4) {
    // prefetch next B before compute
    short8 Bn[4];
    int tn = t + 4;
    if (tn < NT) {
      size_t brow = (size_t)(tn * 16 + l) * KE;
      #pragma unroll
      for (int s = 0; s < 4; ++s) Bn[s] = *(const short8*)(W2T + brow + s * 32 + q * 8);
    }

    float4v C = {0.f, 0.f, 0.f, 0.f};
    #pragma unroll
    for (int s = 0; s < 4; ++s)
      C = __builtin_amdgcn_mfma_f32_16x16x32_bf16(Af[s], Bf[s], C, 0, 0, 0);

    const int eb = m * 16 + q * 4;
    if (t < 174 || t >= 259) {
      // scalar families: i uniform per tile, o per lane; C[row=q*4+r][col=l]
      int c0 = t * 16;
      int fam = (t < 174) ? 0 : 1;
      int cb = fam ? (c0 - 4144) : c0;
      int i = cb / 48;
      int ob = cb - i * 48;                 // 0,16,32
      int aoff = (fam ? 108 : 0) + ob + l;
      float4 fv = *(const float4*)&sF0[fam][i][eb];
      unsafeAtomicAdd(&sInl[eb + 0][aoff], C[0] * fv.x);
      unsafeAtomicAdd(&sInl[eb + 1][aoff], C[1] * fv.y);
      unsafeAtomicAdd(&sInl[eb + 2][aoff], C[2] * fv.z);
      unsafeAtomicAdd(&sInl[eb + 3][aoff], C[3] * fv.w);
    } else {
      // vector families (may mix 1o/1e within a tile): per-lane decode
      int c = t * 16 + l;
      int fi = (c < 3464) ? 0 : 1;
      int rel = c - (fi ? 3464 : 2784);
      int i = rel / 10;
      int o = rel - i * 10;
      int ab = (fi ? 78 : 48) + 3 * o;
      #pragma unroll
      for (int cc = 0; cc < 3; ++cc) {
        const unsigned short* p = &sF1[fi][cc][i][eb];
        ushort2 u01 = *(const ushort2*)p;
        ushort2 u23 = *(const ushort2*)(p + 2);
        unsafeAtomicAdd(&sInl[eb + 0][ab + cc], C[0] * b2f(u01.x));
        unsafeAtomicAdd(&sInl[eb + 1][ab + cc], C[1] * b2f(u01.y));
        unsafeAtomicAdd(&sInl[eb + 2][ab + cc], C[2] * b2f(u23.x));
        unsafeAtomicAdd(&sInl[eb + 3][ab + cc], C[3] * b2f(u23.y));
      }
    }
    #pragma unroll
    for (int s = 0; s < 4; ++s) Bf[s] = Bn[s];
  }
  __syncthreads();

  // ---- scatter to global (native fp atomics) ----
  const float n58 = 0.13130643285972254f, n68 = 0.12126781251816650f;
  for (int idx = tid; idx < EPW * IN_SZ; idx += 512) {
    int e = idx / IN_SZ, o = idx - e * IN_SZ;
    if (e0 + e < NE) {
      float nrm = (o < 48 || o >= 108) ? n58 : n68;
      unsafeAtomicAdd(&acc[(size_t)sSrc[e] * IN_SZ + o], sInl[e][o] * nrm);
    }
  }
}

// ---------------- Kernel 3: out = acc / max(cnt,1) + node_attr ----------------
__global__ __launch_bounds__(256) void finalize_kernel(
    const float* __restrict__ acc, const int* __restrict__ icnt,
    const float* __restrict__ node_attr, float* __restrict__ out)
{
  int idx = blockIdx.x * 256 + threadIdx.x;
  if (idx < NN * IN_SZ) {
    int n = idx / IN_SZ;
    out[idx] = acc[idx] / fmaxf((float)icnt[n], 1.f) + node_attr[idx];
  }
}

extern "C" void kernel_launch(void* const* d_in, const int* in_sizes, int n_in,
                              void* d_out, int out_size, void* d_ws, size_t ws_size,
                              hipStream_t stream)
{
  const float* node_attr  = (const float*)d_in[0];
  const int*   edge_index = (const int*)d_in[1];
  const float* edge_attr  = (const float*)d_in[2];
  const float* edge_sh    = (const float*)d_in[3];
  const float* W1 = (const float*)d_in[4];
  const float* b1 = (const float*)d_in[5];
  const float* W2 = (const float*)d_in[6];
  const float* b2 = (const float*)d_in[7];
  float* out = (float*)d_out;

  unsigned short* h_ext = (unsigned short*)d_ws;              // 50016 * 128 bf16
  unsigned short* W2T   = h_ext + (size_t)50016 * KE;         // 6928 * 128 bf16
  float* acc = (float*)(W2T + (size_t)WN * KE);               // 10000 * 156 f32
  int*   icnt = (int*)(acc + (size_t)NN * IN_SZ);             // 10000 i32

  hipMemsetAsync(acc, 0, ((size_t)NN * IN_SZ + NN) * sizeof(float), stream);
  hipMemsetAsync(h_ext + (size_t)50000 * KE, 0, (size_t)16 * KE * sizeof(unsigned short), stream);
  w2t_kernel<<<(WN * 16 + 255) / 256, 256, 0, stream>>>(W2, b2, W2T);
  mlp1_kernel<<<NE / 8, 256, 0, stream>>>(edge_attr, W1, b1, h_ext);
  tp_kernel<<<(NE + EPW - 1) / EPW, 512, 0, stream>>>(h_ext, node_attr, edge_index,
                                                      edge_sh, W2T, acc, icnt);
  finalize_kernel<<<(NN * IN_SZ + 255) / 256, 256, 0, stream>>>(acc, icnt, node_attr, out);
}

// Round 4
// 535.968 us; speedup vs baseline: 5.3947x; 5.3947x over previous
//
#include <hip/hip_runtime.h>

#define NE 50000
#define NN 10000
#define KH 96
#define KE 128          // padded K: 96 + bias row (=1*b2) + zeros
#define WN 6928
#define WP 7744         // permuted+padded W2 column count = 484 tiles of 16
#define IN_SZ 156
#define EPW 32          // edges per workgroup in tp_kernel

typedef __attribute__((ext_vector_type(8))) short short8;
typedef __attribute__((ext_vector_type(4))) float float4v;

__device__ __forceinline__ unsigned short f2bf(float x) {
  unsigned u = __float_as_uint(x);
  unsigned r = (u + 0x7FFFu + ((u >> 16) & 1u)) >> 16;   // RNE
  return (unsigned short)r;
}
__device__ __forceinline__ float b2f(unsigned short u) {
  return __uint_as_float(((unsigned)u) << 16);
}

// ---------------- Kernel 1: h_ext = [relu(edge_attr @ W1 + b1) | 1 | 0...] in bf16 ----------------
__global__ __launch_bounds__(256) void mlp1_kernel(
    const float* __restrict__ edge_attr, const float* __restrict__ W1,
    const float* __restrict__ b1, unsigned short* __restrict__ h_ext)
{
  __shared__ float ea[8][KH];
  __shared__ float w1s[KH][KH];
  const int tid = threadIdx.x;
  const int e0 = blockIdx.x * 8;

  for (int idx = tid; idx < KH * KH; idx += 256) w1s[idx / KH][idx % KH] = W1[idx];
  for (int idx = tid; idx < 8 * KH; idx += 256) {
    int e = idx / KH, k = idx % KH;
    ea[e][k] = edge_attr[(size_t)(e0 + e) * KH + k];
  }
  __syncthreads();

  const int e = tid >> 5;
  const int lane32 = tid & 31;
  const int j0 = lane32 * 3;
  float a0 = b1[j0], a1 = b1[j0 + 1], a2 = b1[j0 + 2];
  #pragma unroll 8
  for (int k = 0; k < KH; ++k) {
    float v = ea[e][k];
    a0 = fmaf(v, w1s[k][j0], a0);
    a1 = fmaf(v, w1s[k][j0 + 1], a1);
    a2 = fmaf(v, w1s[k][j0 + 2], a2);
  }
  size_t base = (size_t)(e0 + e) * KE;
  h_ext[base + j0]     = f2bf(fmaxf(a0, 0.f));
  h_ext[base + j0 + 1] = f2bf(fmaxf(a1, 0.f));
  h_ext[base + j0 + 2] = f2bf(fmaxf(a2, 0.f));
  h_ext[base + 96 + lane32] = (lane32 == 0) ? (unsigned short)0x3F80 : (unsigned short)0;
}

// ---------------- Kernel P: permuted W2P[np][k] bf16 ----------------
// Column permutation (np -> original W2 column c):
//   [0,2784):      0e block, c = np                     (np = i*48+o)
//   [2784,3872):   1o block padded 10->16: i=(np-2784)/16, o=%16; c = 2784+i*10+o if o<10 else ZERO
//   [3872,4960):   1e block padded:        i=(np-3872)/16, o=%16; c = 3464+i*10+o if o<10 else ZERO
//   [4960,7744):   0o block, c = 4144 + (np-4960)       (= 4144+i*48+o)
// k=96 -> b2[c]; k in (96,128) -> 0.
__global__ __launch_bounds__(256) void w2p_kernel(
    const float* __restrict__ W2, const float* __restrict__ b2,
    unsigned short* __restrict__ W2P)
{
  int idx = blockIdx.x * 256 + threadIdx.x;
  if (idx >= WP * 16) return;
  int np = idx >> 4, ch = idx & 15, k0 = ch * 8;
  int c;
  if (np < 2784) c = np;
  else if (np < 3872) { int rel = np - 2784, i = rel >> 4, o = rel & 15; c = (o < 10) ? 2784 + i * 10 + o : -1; }
  else if (np < 4960) { int rel = np - 3872, i = rel >> 4, o = rel & 15; c = (o < 10) ? 3464 + i * 10 + o : -1; }
  else c = 4144 + (np - 4960);

  unsigned short o8[8];
  #pragma unroll
  for (int j = 0; j < 8; ++j) {
    int k = k0 + j;
    float v = 0.f;
    if (c >= 0) v = (k < KH) ? W2[(size_t)k * WN + c] : (k == KH ? b2[c] : 0.f);
    o8[j] = f2bf(v);
  }
  uint4 pk;
  pk.x = o8[0] | ((unsigned)o8[1] << 16);
  pk.y = o8[2] | ((unsigned)o8[3] << 16);
  pk.z = o8[4] | ((unsigned)o8[5] << 16);
  pk.w = o8[6] | ((unsigned)o8[7] << 16);
  *(uint4*)(W2P + (size_t)np * KE + k0) = pk;
}

// ---------------- Kernel 2: MFMA w-GEMM fused with TP; register i-contraction, no LDS atomics ----
// 512 threads = 8 waves = 8 column groups; each wave covers all 32 edges (2 MFMA halves).
// Groups: wv 0..2 = 0e ob=wv (58 tiles, t=3i+ob);  wv 3 = 1o (68, t=174+i);
//         wv 4 = 1e (68, t=242+i);  wv 5..7 = 0o ob=wv-5 (58, t=310+3i+ob).
__global__ __launch_bounds__(512, 4) void tp_kernel(
    const unsigned short* __restrict__ h_ext, const float* __restrict__ node_attr,
    const int* __restrict__ edge_index, const float* __restrict__ edge_sh,
    const unsigned short* __restrict__ W2P,
    float* __restrict__ acc, int* __restrict__ icnt)
{
  __shared__ float sInl[EPW][165];                 // union: input stage, then sOut[e][156]
  __shared__ float sF0[2][58][EPW];                // scalar feats [fam][i][e]  (0:0e, 1:0o)
  __shared__ unsigned short sF1[2][68][3][EPW];    // vector feats bf16 [fam][i][cc][e]
  __shared__ float sShs[EPW][4];
  __shared__ int sSrc[EPW], sDst[EPW];

  const int tid = threadIdx.x;
  const int e0 = blockIdx.x * EPW;

  if (tid < EPW) {
    int ok = (e0 + tid) < NE;
    int s = ok ? edge_index[e0 + tid] : 0;
    int d = ok ? edge_index[NE + e0 + tid] : 0;
    sSrc[tid] = s; sDst[tid] = d;
    if (ok) atomicAdd(&icnt[s], 1);
  }
  if (tid >= 128 && tid < 128 + EPW * 4) {
    int t2 = tid - 128;
    int e = t2 >> 2, c = t2 & 3;
    sShs[e][c] = ((e0 + e) < NE) ? edge_sh[(size_t)(e0 + e) * 4 + c] : 0.f;
  }
  __syncthreads();

  for (int idx = tid; idx < EPW * IN_SZ; idx += 512) {
    int e = idx / IN_SZ, f = idx - e * IN_SZ;
    sInl[e][f] = node_attr[(size_t)sDst[e] * IN_SZ + f];
  }
  __syncthreads();

  { // ---- feature construction: 16 workers per edge ----
    const int e = tid >> 4, j = tid & 15;
    const float sh0 = sShs[e][0], sx = sShs[e][1], sy = sShs[e][2], sz = sShs[e][3];
    const float i3 = 0.57735026918962576f, i2 = 0.70710678118654752f;
    for (int i = j; i < 48; i += 16) {
      float v0 = sInl[e][i], w0 = sInl[e][108 + i];
      sF0[0][i][e] = v0 * sh0;
      sF0[1][10 + i][e] = w0 * sh0;
      sF1[0][i][0][e] = f2bf(v0 * sx); sF1[0][i][1][e] = f2bf(v0 * sy); sF1[0][i][2][e] = f2bf(v0 * sz);
      sF1[1][20 + i][0][e] = f2bf(w0 * sx); sF1[1][20 + i][1][e] = f2bf(w0 * sy); sF1[1][20 + i][2][e] = f2bf(w0 * sz);
    }
    if (j < 10) {
      const int v = j;
      float ax = sInl[e][48 + 3 * v], ay = sInl[e][48 + 3 * v + 1], az = sInl[e][48 + 3 * v + 2];
      float bx = sInl[e][78 + 3 * v], by = sInl[e][78 + 3 * v + 1], bz = sInl[e][78 + 3 * v + 2];
      sF0[0][48 + v][e] = (ax * sx + ay * sy + az * sz) * i3;
      sF0[1][v][e]      = (bx * sx + by * sy + bz * sz) * i3;
      sF1[0][48 + v][0][e] = f2bf(ax * sh0); sF1[0][48 + v][1][e] = f2bf(ay * sh0); sF1[0][48 + v][2][e] = f2bf(az * sh0);
      sF1[0][58 + v][0][e] = f2bf((by * sz - bz * sy) * i2);
      sF1[0][58 + v][1][e] = f2bf((bz * sx - bx * sz) * i2);
      sF1[0][58 + v][2][e] = f2bf((bx * sy - by * sx) * i2);
      sF1[1][v][0][e] = f2bf((ay * sz - az * sy) * i2);
      sF1[1][v][1][e] = f2bf((az * sx - ax * sz) * i2);
      sF1[1][v][2][e] = f2bf((ax * sy - ay * sx) * i2);
      sF1[1][10 + v][0][e] = f2bf(bx * sh0); sF1[1][10 + v][1][e] = f2bf(by * sh0); sF1[1][10 + v][2][e] = f2bf(bz * sh0);
    }
  }
  __syncthreads();
  // sInl now becomes sOut: every element [e][0..155] is written exactly once below, no zeroing needed.

  const int wv = tid >> 6;            // 0..7 = column group
  const int l = tid & 15, q = (tid >> 4) & 3;

  // A fragments for both edge halves, held in registers for the whole kernel.
  short8 Af[2][4];
  #pragma unroll
  for (int m = 0; m < 2; ++m) {
    size_t erow = (size_t)(e0 + m * 16 + l) * KE;     // h_ext padded to 50016 rows
    #pragma unroll
    for (int s = 0; s < 4; ++s)
      Af[m][s] = *(const short8*)(h_ext + erow + s * 32 + q * 8);
  }

  int fam4, ob = 0, niter, tbase, tstride;
  if (wv < 3)      { fam4 = 0; ob = wv;     niter = 58; tbase = wv;           tstride = 3; }
  else if (wv == 3){ fam4 = 1;              niter = 68; tbase = 174;          tstride = 1; }
  else if (wv == 4){ fam4 = 2;              niter = 68; tbase = 242;          tstride = 1; }
  else             { fam4 = 3; ob = wv - 5; niter = 58; tbase = 310 + wv - 5; tstride = 3; }

  short8 Bf[4];
  {
    size_t brow = (size_t)(tbase * 16 + l) * KE;
    #pragma unroll
    for (int s = 0; s < 4; ++s) Bf[s] = *(const short8*)(W2P + brow + s * 32 + q * 8);
  }

  int t = tbase;
  if (fam4 == 0 || fam4 == 3) {
    // ---------------- scalar families ----------------
    const int sf = (fam4 == 0) ? 0 : 1;
    float r0[4] = {0.f, 0.f, 0.f, 0.f}, r1[4] = {0.f, 0.f, 0.f, 0.f};
    for (int i = 0; i < 58; ++i) {
      short8 Bn[4];
      {
        int tn = (i + 1 < 58) ? t + tstride : t;
        size_t brow = (size_t)(tn * 16 + l) * KE;
        #pragma unroll
        for (int s = 0; s < 4; ++s) Bn[s] = *(const short8*)(W2P + brow + s * 32 + q * 8);
      }
      float4 f0 = *(const float4*)&sF0[sf][i][q * 4];
      float4 f1 = *(const float4*)&sF0[sf][i][16 + q * 4];
      float4v C0 = {0.f, 0.f, 0.f, 0.f}, C1 = {0.f, 0.f, 0.f, 0.f};
      #pragma unroll
      for (int s = 0; s < 4; ++s) {
        C0 = __builtin_amdgcn_mfma_f32_16x16x32_bf16(Af[0][s], Bf[s], C0, 0, 0, 0);
        C1 = __builtin_amdgcn_mfma_f32_16x16x32_bf16(Af[1][s], Bf[s], C1, 0, 0, 0);
      }
      r0[0] += C0[0] * f0.x; r0[1] += C0[1] * f0.y; r0[2] += C0[2] * f0.z; r0[3] += C0[3] * f0.w;
      r1[0] += C1[0] * f1.x; r1[1] += C1[1] * f1.y; r1[2] += C1[2] * f1.z; r1[3] += C1[3] * f1.w;
      #pragma unroll
      for (int s = 0; s < 4; ++s) Bf[s] = Bn[s];
      t += tstride;
    }
    const int col = ((fam4 == 0) ? 0 : 108) + ob * 16 + l;
    #pragma unroll
    for (int r = 0; r < 4; ++r) {
      sInl[q * 4 + r][col]      = r0[r];
      sInl[16 + q * 4 + r][col] = r1[r];
    }
  } else {
    // ---------------- vector families ----------------
    const int vf = fam4 - 1;
    float r0[4][3] = {{0.f}}, r1[4][3] = {{0.f}};
    for (int i = 0; i < 68; ++i) {
      short8 Bn[4];
      {
        int tn = (i + 1 < 68) ? t + 1 : t;
        size_t brow = (size_t)(tn * 16 + l) * KE;
        #pragma unroll
        for (int s = 0; s < 4; ++s) Bn[s] = *(const short8*)(W2P + brow + s * 32 + q * 8);
      }
      ushort4 g0[3], g1[3];
      #pragma unroll
      for (int cc = 0; cc < 3; ++cc) {
        g0[cc] = *(const ushort4*)&sF1[vf][i][cc][q * 4];
        g1[cc] = *(const ushort4*)&sF1[vf][i][cc][16 + q * 4];
      }
      float4v C0 = {0.f, 0.f, 0.f, 0.f}, C1 = {0.f, 0.f, 0.f, 0.f};
      #pragma unroll
      for (int s = 0; s < 4; ++s) {
        C0 = __builtin_amdgcn_mfma_f32_16x16x32_bf16(Af[0][s], Bf[s], C0, 0, 0, 0);
        C1 = __builtin_amdgcn_mfma_f32_16x16x32_bf16(Af[1][s], Bf[s], C1, 0, 0, 0);
      }
      #pragma unroll
      for (int cc = 0; cc < 3; ++cc) {
        r0[0][cc] += C0[0] * b2f(g0[cc].x); r0[1][cc] += C0[1] * b2f(g0[cc].y);
        r0[2][cc] += C0[2] * b2f(g0[cc].z); r0[3][cc] += C0[3] * b2f(g0[cc].w);
        r1[0][cc] += C1[0] * b2f(g1[cc].x); r1[1][cc] += C1[1] * b2f(g1[cc].y);
        r1[2][cc] += C1[2] * b2f(g1[cc].z); r1[3][cc] += C1[3] * b2f(g1[cc].w);
      }
      #pragma unroll
      for (int s = 0; s < 4; ++s) Bf[s] = Bn[s];
      t += 1;
    }
    if (l < 10) {
      const int col = ((vf == 0) ? 48 : 78) + 3 * l;
      #pragma unroll
      for (int r = 0; r < 4; ++r)
        #pragma unroll
        for (int cc = 0; cc < 3; ++cc) {
          sInl[q * 4 + r][col + cc]      = r0[r][cc];
          sInl[16 + q * 4 + r][col + cc] = r1[r][cc];
        }
    }
  }
  __syncthreads();

  // ---- scatter to global ----
  const float n58 = 0.13130643285972254f, n68 = 0.12126781251816650f;
  for (int idx = tid; idx < EPW * IN_SZ; idx += 512) {
    int e = idx / IN_SZ, o = idx - e * IN_SZ;
    if (e0 + e < NE) {
      float nrm = (o < 48 || o >= 108) ? n58 : n68;
      unsafeAtomicAdd(&acc[(size_t)sSrc[e] * IN_SZ + o], sInl[e][o] * nrm);
    }
  }
}

// ---------------- Kernel 3: out = acc / max(cnt,1) + node_attr ----------------
__global__ __launch_bounds__(256) void finalize_kernel(
    const float* __restrict__ acc, const int* __restrict__ icnt,
    const float* __restrict__ node_attr, float* __restrict__ out)
{
  int idx = blockIdx.x * 256 + threadIdx.x;
  if (idx < NN * IN_SZ) {
    int n = idx / IN_SZ;
    out[idx] = acc[idx] / fmaxf((float)icnt[n], 1.f) + node_attr[idx];
  }
}

extern "C" void kernel_launch(void* const* d_in, const int* in_sizes, int n_in,
                              void* d_out, int out_size, void* d_ws, size_t ws_size,
                              hipStream_t stream)
{
  const float* node_attr  = (const float*)d_in[0];
  const int*   edge_index = (const int*)d_in[1];
  const float* edge_attr  = (const float*)d_in[2];
  const float* edge_sh    = (const float*)d_in[3];
  const float* W1 = (const float*)d_in[4];
  const float* b1 = (const float*)d_in[5];
  const float* W2 = (const float*)d_in[6];
  const float* b2 = (const float*)d_in[7];
  float* out = (float*)d_out;

  unsigned short* h_ext = (unsigned short*)d_ws;              // 50016 * 128 bf16
  unsigned short* W2P   = h_ext + (size_t)50016 * KE;         // 7744 * 128 bf16
  float* acc = (float*)(W2P + (size_t)WP * KE);               // 10000 * 156 f32
  int*   icnt = (int*)(acc + (size_t)NN * IN_SZ);             // 10000 i32

  hipMemsetAsync(acc, 0, ((size_t)NN * IN_SZ + NN) * sizeof(float), stream);
  hipMemsetAsync(h_ext + (size_t)50000 * KE, 0, (size_t)16 * KE * sizeof(unsigned short), stream);
  w2p_kernel<<<(WP * 16) / 256, 256, 0, stream>>>(W2, b2, W2P);
  mlp1_kernel<<<NE / 8, 256, 0, stream>>>(edge_attr, W1, b1, h_ext);
  tp_kernel<<<(NE + EPW - 1) / EPW, 512, 0, stream>>>(h_ext, node_attr, edge_index,
                                                      edge_sh, W2P, acc, icnt);
  finalize_kernel<<<(NN * IN_SZ + 255) / 256, 256, 0, stream>>>(acc, icnt, node_attr, out);
}